// Round 1
// baseline (769.522 us; speedup 1.0000x reference)
//
#include <hip/hip_runtime.h>
#include <hip/hip_bf16.h>
#include <math.h>
#include <stdint.h>

#define TT 4096
#define DD 1024
#define FF 4096
#define EE 8
#define LN_EPS 1e-5f

using bf16x8 = __attribute__((ext_vector_type(8))) short;
using f32x4v = __attribute__((ext_vector_type(4))) float;
using u32x4  = __attribute__((ext_vector_type(4))) unsigned int;
using us4    = __attribute__((ext_vector_type(4))) unsigned short;

__device__ __forceinline__ unsigned short f2b(float f) {
  union { float f; unsigned u; } v; v.f = f;
  unsigned r = v.u + 0x7fffu + ((v.u >> 16) & 1u);
  return (unsigned short)(r >> 16);
}
__device__ __forceinline__ float b2f(unsigned short h) {
  union { unsigned u; float f; } v; v.u = ((unsigned)h) << 16; return v.f;
}

__device__ __forceinline__ float blk_sum(float v, float* red) {
  #pragma unroll
  for (int o = 32; o; o >>= 1) v += __shfl_down(v, o);
  int wid = threadIdx.x >> 6;
  if ((threadIdx.x & 63) == 0) red[wid] = v;
  __syncthreads();
  float s = red[0] + red[1] + red[2] + red[3];
  __syncthreads();
  return s;
}

__global__ void k_zero(int* counts) {
  if (threadIdx.x < EE) counts[threadIdx.x] = 0;
}

__global__ void k_scan(const int* __restrict__ counts, int* __restrict__ offsets) {
  if (threadIdx.x == 0) {
    int r = 0;
    for (int e = 0; e < EE; ++e) { offsets[e] = r; r += counts[e]; }
  }
}

// Transpose-convert f32 [R][C] (batched) -> bf16 [C][R]
__global__ __launch_bounds__(256) void k_tr(const float* __restrict__ in,
                                            unsigned short* __restrict__ out,
                                            int R, int C, int ntR, int ntC) {
  int bid = blockIdx.x;
  int tc = bid % ntC; bid /= ntC;
  int tr = bid % ntR; bid /= ntR;
  int b = bid;
  const float* ip = in + (size_t)b * R * C;
  unsigned short* op = out + (size_t)b * R * C;
  __shared__ float tl[64][68];
  int r0 = tr * 64, c0 = tc * 64;
  #pragma unroll
  for (int i = 0; i < 4; i++) {
    int f = threadIdx.x + i * 256;
    int row = f >> 4, cc = (f & 15) * 4;
    float4 v = *(const float4*)(ip + (size_t)(r0 + row) * C + c0 + cc);
    tl[row][cc] = v.x; tl[row][cc + 1] = v.y; tl[row][cc + 2] = v.z; tl[row][cc + 3] = v.w;
  }
  __syncthreads();
  #pragma unroll
  for (int i = 0; i < 4; i++) {
    int f = threadIdx.x + i * 256;
    int row = f >> 4, cc = (f & 15) * 4;
    us4 w;
    w[0] = f2b(tl[cc][row]); w[1] = f2b(tl[cc + 1][row]);
    w[2] = f2b(tl[cc + 2][row]); w[3] = f2b(tl[cc + 3][row]);
    *(us4*)(op + (size_t)(c0 + row) * R + r0 + cc) = w;
  }
}

// mix_w [1024][1024] f32 -> Bp [1024][3072] bf16 rows = [hi | hi | lo] along k
__global__ __launch_bounds__(256) void k_tr_split(const float* __restrict__ in,
                                                  unsigned short* __restrict__ out) {
  int bid = blockIdx.x;
  int tc = bid % 16, tr = bid / 16;
  __shared__ float tl[64][68];
  int r0 = tr * 64, c0 = tc * 64;
  #pragma unroll
  for (int i = 0; i < 4; i++) {
    int f = threadIdx.x + i * 256;
    int row = f >> 4, cc = (f & 15) * 4;
    float4 v = *(const float4*)(in + (size_t)(r0 + row) * 1024 + c0 + cc);
    tl[row][cc] = v.x; tl[row][cc + 1] = v.y; tl[row][cc + 2] = v.z; tl[row][cc + 3] = v.w;
  }
  __syncthreads();
  #pragma unroll
  for (int i = 0; i < 4; i++) {
    int f = threadIdx.x + i * 256;
    int row = f >> 4, cc = (f & 15) * 4;
    us4 hi, lo;
    #pragma unroll
    for (int j = 0; j < 4; j++) {
      float v = tl[cc + j][row];
      unsigned short h = f2b(v);
      hi[j] = h;
      lo[j] = f2b(v - b2f(h));
    }
    unsigned short* row_p = out + (size_t)(c0 + row) * 3072;
    *(us4*)(row_p + r0 + cc) = hi;
    *(us4*)(row_p + 1024 + r0 + cc) = hi;
    *(us4*)(row_p + 2048 + r0 + cc) = lo;
  }
}

// LN1: x [T][D] f32 -> Ap [T][3072] bf16 rows = [hi | lo | hi]
__global__ __launch_bounds__(256) void k_ln1(const float* __restrict__ x,
                                             const float* __restrict__ g,
                                             const float* __restrict__ be,
                                             unsigned short* __restrict__ Ap) {
  __shared__ float red[4];
  int t = blockIdx.x;
  const float* xr = x + (size_t)t * DD;
  int d0 = threadIdx.x * 4;
  float4 xv = *(const float4*)(xr + d0);
  float mu = blk_sum((xv.x + xv.y) + (xv.z + xv.w), red) * (1.f / DD);
  float dx0 = xv.x - mu, dx1 = xv.y - mu, dx2 = xv.z - mu, dx3 = xv.w - mu;
  float var = blk_sum(dx0 * dx0 + dx1 * dx1 + dx2 * dx2 + dx3 * dx3, red) * (1.f / DD);
  float rs = rsqrtf(var + LN_EPS);
  float4 gv = *(const float4*)(g + d0);
  float4 bv = *(const float4*)(be + d0);
  float n0 = dx0 * rs * gv.x + bv.x, n1 = dx1 * rs * gv.y + bv.y;
  float n2 = dx2 * rs * gv.z + bv.z, n3 = dx3 * rs * gv.w + bv.w;
  us4 hi, lo;
  float nn[4] = {n0, n1, n2, n3};
  #pragma unroll
  for (int j = 0; j < 4; j++) {
    unsigned short h = f2b(nn[j]);
    hi[j] = h;
    lo[j] = f2b(nn[j] - b2f(h));
  }
  unsigned short* row = Ap + (size_t)t * 3072;
  *(us4*)(row + d0) = hi;
  *(us4*)(row + 1024 + d0) = lo;
  *(us4*)(row + 2048 + d0) = hi;
}

// LN2 + router + top2 dispatch + out init (residual + combine-weighted b2)
__global__ __launch_bounds__(256) void k_ln2r(const float* __restrict__ x1,
                                              const float* __restrict__ g2,
                                              const float* __restrict__ be2,
                                              const float* __restrict__ rw,
                                              const float* __restrict__ b2,
                                              unsigned short* __restrict__ n2b,
                                              float* __restrict__ out,
                                              int* __restrict__ counts,
                                              int* __restrict__ toks,
                                              float* __restrict__ tws) {
  __shared__ float red[4];
  __shared__ float lred[4][8];
  __shared__ int isel[2];
  __shared__ float wsel[2];
  int t = blockIdx.x, tid = threadIdx.x;
  const float* xr = x1 + (size_t)t * DD;
  int d0 = tid * 4;
  float4 xv = *(const float4*)(xr + d0);
  float mu = blk_sum((xv.x + xv.y) + (xv.z + xv.w), red) * (1.f / DD);
  float dx0 = xv.x - mu, dx1 = xv.y - mu, dx2 = xv.z - mu, dx3 = xv.w - mu;
  float var = blk_sum(dx0 * dx0 + dx1 * dx1 + dx2 * dx2 + dx3 * dx3, red) * (1.f / DD);
  float rs = rsqrtf(var + LN_EPS);
  float4 gv = *(const float4*)(g2 + d0);
  float4 bv = *(const float4*)(be2 + d0);
  float nn[4];
  nn[0] = dx0 * rs * gv.x + bv.x; nn[1] = dx1 * rs * gv.y + bv.y;
  nn[2] = dx2 * rs * gv.z + bv.z; nn[3] = dx3 * rs * gv.w + bv.w;
  us4 nh;
  #pragma unroll
  for (int j = 0; j < 4; j++) nh[j] = f2b(nn[j]);
  *(us4*)(n2b + (size_t)t * DD + d0) = nh;
  // router partials: rw is [D][E]
  float pl[8] = {0, 0, 0, 0, 0, 0, 0, 0};
  #pragma unroll
  for (int j = 0; j < 4; j++) {
    const float4* rp = (const float4*)(rw + (size_t)(d0 + j) * 8);
    float4 r0 = rp[0], r1 = rp[1];
    float nv = nn[j];
    pl[0] += nv * r0.x; pl[1] += nv * r0.y; pl[2] += nv * r0.z; pl[3] += nv * r0.w;
    pl[4] += nv * r1.x; pl[5] += nv * r1.y; pl[6] += nv * r1.z; pl[7] += nv * r1.w;
  }
  int wid = tid >> 6, lane = tid & 63;
  #pragma unroll
  for (int e = 0; e < 8; e++) {
    float v = pl[e];
    #pragma unroll
    for (int o = 32; o; o >>= 1) v += __shfl_down(v, o);
    if (lane == 0) lred[wid][e] = v;
  }
  __syncthreads();
  if (tid == 0) {
    float lg[8];
    #pragma unroll
    for (int e = 0; e < 8; e++) lg[e] = lred[0][e] + lred[1][e] + lred[2][e] + lred[3][e];
    float m = lg[0];
    for (int e = 1; e < 8; e++) m = fmaxf(m, lg[e]);
    float p[8], sum = 0.f;
    for (int e = 0; e < 8; e++) { p[e] = expf(lg[e] - m); sum += p[e]; }
    float inv = 1.f / sum;
    for (int e = 0; e < 8; e++) p[e] *= inv;
    int e0 = 0; float b0 = p[0];
    for (int e = 1; e < 8; e++) if (p[e] > b0) { b0 = p[e]; e0 = e; }
    int e1 = -1; float b1v = -1.f;
    for (int e = 0; e < 8; e++) if (e != e0 && p[e] > b1v) { b1v = p[e]; e1 = e; }
    int s0 = atomicAdd(&counts[e0], 1);
    toks[e0 * TT + s0] = t; tws[e0 * TT + s0] = b0;
    int s1 = atomicAdd(&counts[e1], 1);
    toks[e1 * TT + s1] = t; tws[e1 * TT + s1] = b1v;
    isel[0] = e0; isel[1] = e1; wsel[0] = b0; wsel[1] = b1v;
  }
  __syncthreads();
  int e0 = isel[0], e1 = isel[1];
  float w0 = wsel[0], w1 = wsel[1];
  float4 ba = *(const float4*)(b2 + (size_t)e0 * DD + d0);
  float4 bb = *(const float4*)(b2 + (size_t)e1 * DD + d0);
  float4 o;
  o.x = xv.x + w0 * ba.x + w1 * bb.x;
  o.y = xv.y + w0 * ba.y + w1 * bb.y;
  o.z = xv.z + w0 * ba.z + w1 * bb.z;
  o.w = xv.w + w0 * ba.w + w1 * bb.w;
  *(float4*)(out + (size_t)t * DD + d0) = o;
}

// Shared 128x128-tile bf16 MFMA GEMM.
// MODE 0: mixer  — A=Ap [T][3072], B=Bp [1024][3072], epilogue x1 = x + n1 + acc + mix_b
// MODE 1: FFN1   — A=n2b gathered rows, B=w1T [E][F][D], epilogue h = silu(acc + b1) (bf16)
// MODE 2: FFN2   — A=h rows, B=w2T [E][D][F], epilogue atomicAdd(out, w*acc)
template <int MODE>
__global__ __launch_bounds__(256, 2) void k_gemm(
    const unsigned short* __restrict__ A,
    const unsigned short* __restrict__ B,
    const float* __restrict__ bias,
    const float* __restrict__ xres,
    float* __restrict__ outf,
    unsigned short* __restrict__ outh,
    const int* __restrict__ counts,
    const int* __restrict__ offsets,
    const int* __restrict__ toks,
    const float* __restrict__ tws) {
  constexpr int KD = (MODE == 0 ? 3072 : (MODE == 1 ? 1024 : 4096));
  constexpr int ND = (MODE == 1 ? 4096 : 1024);
  constexpr int NT = ND / 128;
  constexpr int KT = KD / 64;
  int bid = blockIdx.x;
  int nt = bid % NT; bid /= NT;
  int mt = bid % 32;
  int e = bid / 32;
  int m0 = mt * 128, n0 = nt * 128;
  int count = TT;
  if (MODE != 0) {
    count = counts[e];
    if (m0 >= count) return;
  }
  int lane = threadIdx.x & 63, wid = threadIdx.x >> 6;

  __shared__ unsigned short As[128 * 64];
  __shared__ unsigned short Bs[128 * 64];

  const unsigned short* aRow[4];
  const unsigned short* bRow[4];
  int rloc[4];
  #pragma unroll
  for (int i = 0; i < 4; i++) {
    int q = wid * 4 + i;
    int row = q * 8 + (lane >> 3);
    rloc[i] = row;
    int gm;
    if (MODE == 0) gm = m0 + row;
    else {
      int rr = min(m0 + row, count - 1);
      if (MODE == 1) gm = toks[e * TT + rr];
      else gm = offsets[e] + rr;
    }
    aRow[i] = A + (size_t)gm * KD + (lane & 7) * 8;
    size_t brow = (size_t)(MODE == 0 ? 0 : e) * ND + n0 + row;
    bRow[i] = B + brow * KD + (lane & 7) * 8;
  }

  f32x4v acc[4][4] = {};
  u32x4 ra[4], rb[4], ra2[4], rb2[4];
  #pragma unroll
  for (int i = 0; i < 4; i++) {
    ra[i] = *(const u32x4*)(aRow[i]);
    rb[i] = *(const u32x4*)(bRow[i]);
  }
  int wm = (wid >> 1) * 64, wn = (wid & 1) * 64;

  for (int kt = 0; kt < KT; ++kt) {
    #pragma unroll
    for (int i = 0; i < 4; i++) {
      int row = rloc[i];
      int slot = (lane & 7) ^ (row & 7);
      *(u32x4*)&As[row * 64 + slot * 8] = ra[i];
      *(u32x4*)&Bs[row * 64 + slot * 8] = rb[i];
    }
    __syncthreads();
    bool more = (kt + 1 < KT);
    if (more) {
      int ko = (kt + 1) * 64;
      #pragma unroll
      for (int i = 0; i < 4; i++) {
        ra2[i] = *(const u32x4*)(aRow[i] + ko);
        rb2[i] = *(const u32x4*)(bRow[i] + ko);
      }
    }
    #pragma unroll
    for (int kk = 0; kk < 2; kk++) {
      bf16x8 af[4], bfr[4];
      #pragma unroll
      for (int mi = 0; mi < 4; mi++) {
        int r = wm + mi * 16 + (lane & 15);
        int kg = (lane >> 4) + kk * 4;
        af[mi] = *(const bf16x8*)&As[r * 64 + ((kg ^ (r & 7)) * 8)];
      }
      #pragma unroll
      for (int ni = 0; ni < 4; ni++) {
        int r = wn + ni * 16 + (lane & 15);
        int kg = (lane >> 4) + kk * 4;
        bfr[ni] = *(const bf16x8*)&Bs[r * 64 + ((kg ^ (r & 7)) * 8)];
      }
      #pragma unroll
      for (int mi = 0; mi < 4; mi++)
        #pragma unroll
        for (int ni = 0; ni < 4; ni++)
          acc[mi][ni] = __builtin_amdgcn_mfma_f32_16x16x32_bf16(af[mi], bfr[ni], acc[mi][ni], 0, 0, 0);
    }
    __syncthreads();
    if (more) {
      #pragma unroll
      for (int i = 0; i < 4; i++) { ra[i] = ra2[i]; rb[i] = rb2[i]; }
    }
  }

  // epilogue
  #pragma unroll
  for (int mi = 0; mi < 4; mi++) {
    #pragma unroll
    for (int r = 0; r < 4; r++) {
      int row = wm + mi * 16 + ((lane >> 4) * 4) + r;
      int gr = m0 + row;
      bool valid = (MODE == 0) || (m0 + row < count);
      int tk = 0; float w = 0.f;
      if (MODE == 2) {
        if (valid) { tk = toks[e * TT + gr]; w = tws[e * TT + gr]; }
      }
      #pragma unroll
      for (int ni = 0; ni < 4; ni++) {
        int col = wn + ni * 16 + (lane & 15);
        int gc = n0 + col;
        float v = acc[mi][ni][r];
        if (MODE == 0) {
          float n1v = b2f(A[(size_t)gr * 3072 + gc]) + b2f(A[(size_t)gr * 3072 + 1024 + gc]);
          outf[(size_t)gr * DD + gc] = xres[(size_t)gr * DD + gc] + n1v + v + bias[gc];
        } else if (MODE == 1) {
          if (valid) {
            v += bias[(size_t)e * FF + gc];
            float sv = v / (1.f + expf(-v));
            outh[(size_t)(offsets[e] + gr) * FF + gc] = f2b(sv);
          }
        } else {
          if (valid) atomicAdd(&outf[(size_t)tk * DD + gc], w * v);
        }
      }
    }
  }
}

extern "C" void kernel_launch(void* const* d_in, const int* in_sizes, int n_in,
                              void* d_out, int out_size, void* d_ws, size_t ws_size,
                              hipStream_t stream) {
  const float* x     = (const float*)d_in[0];
  const float* g1    = (const float*)d_in[1];
  const float* be1   = (const float*)d_in[2];
  const float* mix_w = (const float*)d_in[3];
  const float* mix_b = (const float*)d_in[4];
  const float* g2    = (const float*)d_in[5];
  const float* be2   = (const float*)d_in[6];
  const float* rw    = (const float*)d_in[7];
  const float* w1    = (const float*)d_in[8];
  const float* b1    = (const float*)d_in[9];
  const float* w2    = (const float*)d_in[10];
  const float* b2    = (const float*)d_in[11];
  float* out = (float*)d_out;

  char* ws = (char*)d_ws;
  size_t off = 0;
  auto alloc = [&](size_t bytes) -> void* {
    void* p = ws + off;
    off += (bytes + 255) & ~(size_t)255;
    return p;
  };
  unsigned short* Ap  = (unsigned short*)alloc((size_t)TT * 3072 * 2);
  unsigned short* Bp  = (unsigned short*)alloc((size_t)1024 * 3072 * 2);
  unsigned short* w1T = (unsigned short*)alloc((size_t)EE * FF * DD * 2);
  unsigned short* w2T = (unsigned short*)alloc((size_t)EE * DD * FF * 2);
  float* x1           = (float*)alloc((size_t)TT * DD * 4);
  unsigned short* n2b = (unsigned short*)alloc((size_t)TT * DD * 2);
  unsigned short* h   = (unsigned short*)alloc((size_t)2 * TT * FF * 2);
  int* toks           = (int*)alloc((size_t)EE * TT * 4);
  float* tws          = (float*)alloc((size_t)EE * TT * 4);
  int* counts         = (int*)alloc(256);
  int* offsets        = (int*)alloc(256);

  k_zero<<<1, 64, 0, stream>>>(counts);
  k_tr_split<<<16 * 16, 256, 0, stream>>>(mix_w, Bp);
  k_tr<<<EE * 16 * 64, 256, 0, stream>>>(w1, w1T, 1024, 4096, 16, 64);
  k_tr<<<EE * 64 * 16, 256, 0, stream>>>(w2, w2T, 4096, 1024, 64, 16);
  k_ln1<<<TT, 256, 0, stream>>>(x, g1, be1, Ap);
  k_gemm<0><<<32 * 8, 256, 0, stream>>>(Ap, Bp, mix_b, x, x1, nullptr,
                                        nullptr, nullptr, nullptr, nullptr);
  k_ln2r<<<TT, 256, 0, stream>>>(x1, g2, be2, rw, b2, n2b, out, counts, toks, tws);
  k_scan<<<1, 1, 0, stream>>>(counts, offsets);
  k_gemm<1><<<EE * 32 * 32, 256, 0, stream>>>(n2b, w1T, b1, nullptr, nullptr, h,
                                              counts, offsets, toks, tws);
  k_gemm<2><<<EE * 32 * 8, 256, 0, stream>>>(h, w2T, nullptr, nullptr, out, nullptr,
                                             counts, offsets, toks, tws);
}